// Round 1
// baseline (1040.451 us; speedup 1.0000x reference)
//
#include <hip/hip_runtime.h>

#define N_NODES 8192
#define IN_DIM  128
#define HDIM    256
#define NEDGE   131072

// ---------------- copy (vectorized) ----------------
__global__ void copy_f4(const float4* __restrict__ in, float4* __restrict__ out, int n4) {
    int i = blockIdx.x * blockDim.x + threadIdx.x;
    if (i < n4) out[i] = in[i];
}

// ---------------- scatter-add: h[dst[e]] += x[src[e]] ----------------
template<int D>
__global__ void scatter_add(const float* __restrict__ x, const int* __restrict__ src,
                            const int* __restrict__ dst, float* __restrict__ h) {
    constexpr int C = D / 4;                       // float4 chunks per node row
    int gid = blockIdx.x * blockDim.x + threadIdx.x;
    int e = gid / C;
    int c = gid - e * C;
    if (e >= NEDGE) return;
    int s = src[e], d = dst[e];
    float4 v = reinterpret_cast<const float4*>(x)[(size_t)s * C + c];
    float* hp = h + (size_t)d * D + c * 4;
    atomicAdd(hp + 0, v.x);
    atomicAdd(hp + 1, v.y);
    atomicAdd(hp + 2, v.z);
    atomicAdd(hp + 3, v.w);
}

// ---------------- fused GEMM + bias + relu ----------------
// C[M,256] = relu(A[M,K] @ B[K,256] + bias), M = 8192
template<int K>
__global__ __launch_bounds__(256) void gemm_bias_relu(
    const float* __restrict__ A, const float* __restrict__ B,
    const float* __restrict__ bias, float* __restrict__ C) {
    constexpr int BM = 64, BN = 64, BK = 16;
    __shared__ float As[BK][BM];   // transposed A tile: As[k][m]
    __shared__ float Bs[BK][BN];
    const int tid = threadIdx.x;
    const int tx = tid & 15, ty = tid >> 4;
    const int am = tid >> 2, akq = tid & 3;        // A-tile load: row am, k-quad akq
    const int bk = tid >> 4, bn = (tid & 15) * 4;  // B-tile load: row bk, col bn
    const int row0 = blockIdx.y * BM, col0 = blockIdx.x * BN;
    float acc[4][4] = {};
    for (int t = 0; t < K; t += BK) {
        float4 av = *reinterpret_cast<const float4*>(&A[(size_t)(row0 + am) * K + t + akq * 4]);
        float4 bv = *reinterpret_cast<const float4*>(&B[(size_t)(t + bk) * HDIM + col0 + bn]);
        __syncthreads();
        As[akq * 4 + 0][am] = av.x;
        As[akq * 4 + 1][am] = av.y;
        As[akq * 4 + 2][am] = av.z;
        As[akq * 4 + 3][am] = av.w;
        *reinterpret_cast<float4*>(&Bs[bk][bn]) = bv;
        __syncthreads();
#pragma unroll
        for (int kk = 0; kk < BK; ++kk) {
            float4 a4 = *reinterpret_cast<const float4*>(&As[kk][ty * 4]);
            float4 b4 = *reinterpret_cast<const float4*>(&Bs[kk][tx * 4]);
            float a[4] = {a4.x, a4.y, a4.z, a4.w};
            float b[4] = {b4.x, b4.y, b4.z, b4.w};
#pragma unroll
            for (int i = 0; i < 4; ++i)
#pragma unroll
                for (int j = 0; j < 4; ++j)
                    acc[i][j] = fmaf(a[i], b[j], acc[i][j]);
        }
    }
    float4 bb = *reinterpret_cast<const float4*>(&bias[col0 + tx * 4]);
    float bcol[4] = {bb.x, bb.y, bb.z, bb.w};
#pragma unroll
    for (int i = 0; i < 4; ++i) {
        int row = row0 + ty * 4 + i;
        float4 r;
        r.x = fmaxf(acc[i][0] + bcol[0], 0.f);
        r.y = fmaxf(acc[i][1] + bcol[1], 0.f);
        r.z = fmaxf(acc[i][2] + bcol[2], 0.f);
        r.w = fmaxf(acc[i][3] + bcol[3], 0.f);
        *reinterpret_cast<float4*>(&C[(size_t)row * HDIM + col0 + tx * 4]) = r;
    }
}

// ---------------- fold w_out into the edge head ----------------
// v[0:256]   = w_out @ w_edge[:256]      (per-row dot)
// v[256:512] = w_out @ w_edge[256:]
// v[512]     = dot(b_out, w_edge[:256]) + b_edge[0]
// v[513]     = dot(b_out, w_edge[256:])
__global__ void prep_vec(const float* __restrict__ w_out, const float* __restrict__ b_out,
                         const float* __restrict__ w_edge, const float* __restrict__ b_edge,
                         float* __restrict__ v) {
    int c = threadIdx.x;  // 256 threads
    float sa = 0.f, sb = 0.f;
    for (int k = 0; k < HDIM; k += 4) {
        float4 w  = *reinterpret_cast<const float4*>(&w_out[(size_t)c * HDIM + k]);
        float4 ua = *reinterpret_cast<const float4*>(&w_edge[k]);
        float4 ub = *reinterpret_cast<const float4*>(&w_edge[HDIM + k]);
        sa += w.x * ua.x + w.y * ua.y + w.z * ua.z + w.w * ua.w;
        sb += w.x * ub.x + w.y * ub.y + w.z * ub.z + w.w * ub.w;
    }
    v[c] = sa;
    v[HDIM + c] = sb;
    __shared__ float ra[HDIM], rb[HDIM];
    ra[c] = b_out[c] * w_edge[c];
    rb[c] = b_out[c] * w_edge[HDIM + c];
    __syncthreads();
    for (int s = 128; s > 0; s >>= 1) {
        if (c < s) { ra[c] += ra[c + s]; rb[c] += rb[c + s]; }
        __syncthreads();
    }
    if (c == 0) { v[512] = ra[0] + b_edge[0]; v[513] = rb[0]; }
}

// ---------------- li/lj: one wave per node ----------------
__global__ void lilj_kernel(const float* __restrict__ x2, const float* __restrict__ v,
                            float* __restrict__ li, float* __restrict__ lj) {
    int lane = threadIdx.x & 63;
    int wv = threadIdx.x >> 6;
    int node = blockIdx.x * 4 + wv;
    float4 xa = reinterpret_cast<const float4*>(x2)[(size_t)node * 64 + lane];
    float4 va = reinterpret_cast<const float4*>(v)[lane];
    float4 vb = reinterpret_cast<const float4*>(v + HDIM)[lane];
    float a = xa.x * va.x + xa.y * va.y + xa.z * va.z + xa.w * va.w;
    float b = xa.x * vb.x + xa.y * vb.y + xa.z * vb.z + xa.w * vb.w;
#pragma unroll
    for (int off = 32; off > 0; off >>= 1) {
        a += __shfl_down(a, off);
        b += __shfl_down(b, off);
    }
    if (lane == 0) {
        li[node] = a + v[512];
        lj[node] = b + v[513];
    }
}

// ---------------- final: out[i][j] = li[i] + lj[j] ----------------
__global__ void edge_out(const float* __restrict__ li, const float* __restrict__ lj,
                         float* __restrict__ out) {
    int i = blockIdx.y;
    int j4 = blockIdx.x * blockDim.x + threadIdx.x;  // 0..2047 (float4 per row)
    float a = li[i];
    float4 b = reinterpret_cast<const float4*>(lj)[j4];
    float4 r = {a + b.x, a + b.y, a + b.z, a + b.w};
    reinterpret_cast<float4*>(out)[(size_t)i * (N_NODES / 4) + j4] = r;
}

extern "C" void kernel_launch(void* const* d_in, const int* in_sizes, int n_in,
                              void* d_out, int out_size, void* d_ws, size_t ws_size,
                              hipStream_t stream) {
    const float* x      = (const float*)d_in[0];
    const int*   ei     = (const int*)d_in[1];
    const float* w0a    = (const float*)d_in[2];
    const float* b0a    = (const float*)d_in[3];
    const float* w0b    = (const float*)d_in[4];
    const float* b0b    = (const float*)d_in[5];
    const float* w1a    = (const float*)d_in[6];
    const float* b1a    = (const float*)d_in[7];
    const float* w1b    = (const float*)d_in[8];
    const float* b1b    = (const float*)d_in[9];
    const float* w_out  = (const float*)d_in[10];
    const float* b_out  = (const float*)d_in[11];
    const float* w_edge = (const float*)d_in[12];
    const float* b_edge = (const float*)d_in[13];
    const int* src = ei;
    const int* dst = ei + NEDGE;

    float* ws  = (float*)d_ws;
    float* h0  = ws;                                  // N*128
    float* t01 = h0  + (size_t)N_NODES * IN_DIM;      // N*256 (t0, then t1)
    float* x12 = t01 + (size_t)N_NODES * HDIM;        // N*256 (x1, then x2)
    float* h1  = x12 + (size_t)N_NODES * HDIM;        // N*256
    float* v   = h1  + (size_t)N_NODES * HDIM;        // 544
    float* li  = v + 544;                             // N
    float* lj  = li + N_NODES;                        // N
    float* out = (float*)d_out;

    dim3 gGemm(HDIM / 64, N_NODES / 64);

    // ---- layer 0 ----
    copy_f4<<<N_NODES * IN_DIM / 4 / 256, 256, 0, stream>>>(
        (const float4*)x, (float4*)h0, N_NODES * IN_DIM / 4);
    scatter_add<IN_DIM><<<NEDGE * (IN_DIM / 4) / 256, 256, 0, stream>>>(x, src, dst, h0);
    gemm_bias_relu<IN_DIM><<<gGemm, 256, 0, stream>>>(h0, w0a, b0a, t01);
    gemm_bias_relu<HDIM><<<gGemm, 256, 0, stream>>>(t01, w0b, b0b, x12);

    // ---- layer 1 ----
    copy_f4<<<N_NODES * HDIM / 4 / 256, 256, 0, stream>>>(
        (const float4*)x12, (float4*)h1, N_NODES * HDIM / 4);
    scatter_add<HDIM><<<NEDGE * (HDIM / 4) / 256, 256, 0, stream>>>(x12, src, dst, h1);
    gemm_bias_relu<HDIM><<<gGemm, 256, 0, stream>>>(h1, w1a, b1a, t01);
    gemm_bias_relu<HDIM><<<gGemm, 256, 0, stream>>>(t01, w1b, b1b, x12);

    // ---- edge head (w_out folded into two 256-vectors) ----
    prep_vec<<<1, 256, 0, stream>>>(w_out, b_out, w_edge, b_edge, v);
    lilj_kernel<<<N_NODES / 4, 256, 0, stream>>>(x12, v, li, lj);
    edge_out<<<dim3(N_NODES / 4 / 256, N_NODES), 256, 0, stream>>>(li, lj, out);
}

// Round 3
// 428.163 us; speedup vs baseline: 2.4300x; 2.4300x over previous
//
#include <hip/hip_runtime.h>

#define N_NODES 8192
#define IN_DIM  128
#define HDIM    256
#define NEDGE   131072

// ================= CSR build =================
__global__ void hist_kernel(const int* __restrict__ dst, int* __restrict__ deg) {
    int e = blockIdx.x * blockDim.x + threadIdx.x;
    if (e < NEDGE) atomicAdd(&deg[dst[e]], 1);
}

// single block, 1024 threads, scans 8192 degrees -> offs[8193], cursor copy
__global__ __launch_bounds__(1024) void build_scan(const int* __restrict__ deg,
                                                   int* __restrict__ offs,
                                                   int* __restrict__ cursor) {
    __shared__ int part[1024];
    int t = threadIdx.x;
    int base = t * 8;
    int local[8];
    int s = 0;
#pragma unroll
    for (int i = 0; i < 8; ++i) { local[i] = s; s += deg[base + i]; }
    part[t] = s;
    __syncthreads();
    for (int off = 1; off < 1024; off <<= 1) {
        int v = (t >= off) ? part[t - off] : 0;
        __syncthreads();
        part[t] += v;
        __syncthreads();
    }
    int prefix = (t == 0) ? 0 : part[t - 1];
#pragma unroll
    for (int i = 0; i < 8; ++i) {
        int o = prefix + local[i];
        offs[base + i] = o;
        cursor[base + i] = o;
    }
    if (t == 1023) offs[N_NODES] = part[1023];
}

__global__ void fill_kernel(const int* __restrict__ src, const int* __restrict__ dst,
                            int* __restrict__ cursor, int* __restrict__ bucket) {
    int e = blockIdx.x * blockDim.x + threadIdx.x;
    if (e >= NEDGE) return;
    int p = atomicAdd(&cursor[dst[e]], 1);
    bucket[p] = src[e];
}

// ================= gather aggregation: h[n] = x[n] + sum_{s in N(n)} x[s] =================
// one wave per node, float4 per lane (D=256)
__global__ __launch_bounds__(256) void aggregate256(const float* __restrict__ x,
                                                    const int* __restrict__ offs,
                                                    const int* __restrict__ bucket,
                                                    float* __restrict__ h) {
    int lane = threadIdx.x & 63;
    int node = blockIdx.x * 4 + (threadIdx.x >> 6);
    const float4* x4 = reinterpret_cast<const float4*>(x);
    float4 acc = x4[(size_t)node * 64 + lane];
    int b = offs[node], e = offs[node + 1];
    int k = b;
    for (; k + 1 < e; k += 2) {
        int s0 = bucket[k], s1 = bucket[k + 1];
        float4 v0 = x4[(size_t)s0 * 64 + lane];
        float4 v1 = x4[(size_t)s1 * 64 + lane];
        acc.x += v0.x + v1.x; acc.y += v0.y + v1.y;
        acc.z += v0.z + v1.z; acc.w += v0.w + v1.w;
    }
    if (k < e) {
        int s0 = bucket[k];
        float4 v0 = x4[(size_t)s0 * 64 + lane];
        acc.x += v0.x; acc.y += v0.y; acc.z += v0.z; acc.w += v0.w;
    }
    reinterpret_cast<float4*>(h)[(size_t)node * 64 + lane] = acc;
}

// one wave per node, float2 per lane (D=128)
__global__ __launch_bounds__(256) void aggregate128(const float* __restrict__ x,
                                                    const int* __restrict__ offs,
                                                    const int* __restrict__ bucket,
                                                    float* __restrict__ h) {
    int lane = threadIdx.x & 63;
    int node = blockIdx.x * 4 + (threadIdx.x >> 6);
    const float2* x2 = reinterpret_cast<const float2*>(x);
    float2 acc = x2[(size_t)node * 64 + lane];
    int b = offs[node], e = offs[node + 1];
    int k = b;
    for (; k + 1 < e; k += 2) {
        int s0 = bucket[k], s1 = bucket[k + 1];
        float2 v0 = x2[(size_t)s0 * 64 + lane];
        float2 v1 = x2[(size_t)s1 * 64 + lane];
        acc.x += v0.x + v1.x; acc.y += v0.y + v1.y;
    }
    if (k < e) {
        int s0 = bucket[k];
        float2 v0 = x2[(size_t)s0 * 64 + lane];
        acc.x += v0.x; acc.y += v0.y;
    }
    reinterpret_cast<float2*>(h)[(size_t)node * 64 + lane] = acc;
}

// ================= fused GEMM + bias + relu =================
// C[M,256] = relu(A[M,K] @ B[K,256] + bias), M = 8192
template<int K>
__global__ __launch_bounds__(256) void gemm_bias_relu(
    const float* __restrict__ A, const float* __restrict__ B,
    const float* __restrict__ bias, float* __restrict__ C) {
    constexpr int BM = 64, BN = 64, BK = 16;
    __shared__ float As[BK][BM];
    __shared__ float Bs[BK][BN];
    const int tid = threadIdx.x;
    const int tx = tid & 15, ty = tid >> 4;
    const int am = tid >> 2, akq = tid & 3;
    const int bk = tid >> 4, bn = (tid & 15) * 4;
    const int row0 = blockIdx.y * BM, col0 = blockIdx.x * BN;
    float acc[4][4] = {};
    for (int t = 0; t < K; t += BK) {
        float4 av = *reinterpret_cast<const float4*>(&A[(size_t)(row0 + am) * K + t + akq * 4]);
        float4 bv = *reinterpret_cast<const float4*>(&B[(size_t)(t + bk) * HDIM + col0 + bn]);
        __syncthreads();
        As[akq * 4 + 0][am] = av.x;
        As[akq * 4 + 1][am] = av.y;
        As[akq * 4 + 2][am] = av.z;
        As[akq * 4 + 3][am] = av.w;
        *reinterpret_cast<float4*>(&Bs[bk][bn]) = bv;
        __syncthreads();
#pragma unroll
        for (int kk = 0; kk < BK; ++kk) {
            float4 a4 = *reinterpret_cast<const float4*>(&As[kk][ty * 4]);
            float4 b4 = *reinterpret_cast<const float4*>(&Bs[kk][tx * 4]);
            float a[4] = {a4.x, a4.y, a4.z, a4.w};
            float b[4] = {b4.x, b4.y, b4.z, b4.w};
#pragma unroll
            for (int i = 0; i < 4; ++i)
#pragma unroll
                for (int j = 0; j < 4; ++j)
                    acc[i][j] = fmaf(a[i], b[j], acc[i][j]);
        }
    }
    float4 bb = *reinterpret_cast<const float4*>(&bias[col0 + tx * 4]);
    float bcol[4] = {bb.x, bb.y, bb.z, bb.w};
#pragma unroll
    for (int i = 0; i < 4; ++i) {
        int row = row0 + ty * 4 + i;
        float4 r;
        r.x = fmaxf(acc[i][0] + bcol[0], 0.f);
        r.y = fmaxf(acc[i][1] + bcol[1], 0.f);
        r.z = fmaxf(acc[i][2] + bcol[2], 0.f);
        r.w = fmaxf(acc[i][3] + bcol[3], 0.f);
        *reinterpret_cast<float4*>(&C[(size_t)row * HDIM + col0 + tx * 4]) = r;
    }
}

// ================= edge head: fold w_out =================
__global__ void prep_vec(const float* __restrict__ w_out, const float* __restrict__ b_out,
                         const float* __restrict__ w_edge, const float* __restrict__ b_edge,
                         float* __restrict__ v) {
    int c = threadIdx.x;  // 256 threads
    float sa = 0.f, sb = 0.f;
    for (int k = 0; k < HDIM; k += 4) {
        float4 w  = *reinterpret_cast<const float4*>(&w_out[(size_t)c * HDIM + k]);
        float4 ua = *reinterpret_cast<const float4*>(&w_edge[k]);
        float4 ub = *reinterpret_cast<const float4*>(&w_edge[HDIM + k]);
        sa += w.x * ua.x + w.y * ua.y + w.z * ua.z + w.w * ua.w;
        sb += w.x * ub.x + w.y * ub.y + w.z * ub.z + w.w * ub.w;
    }
    v[c] = sa;
    v[HDIM + c] = sb;
    __shared__ float ra[HDIM], rb[HDIM];
    ra[c] = b_out[c] * w_edge[c];
    rb[c] = b_out[c] * w_edge[HDIM + c];
    __syncthreads();
    for (int s = 128; s > 0; s >>= 1) {
        if (c < s) { ra[c] += ra[c + s]; rb[c] += rb[c + s]; }
        __syncthreads();
    }
    if (c == 0) { v[512] = ra[0] + b_edge[0]; v[513] = rb[0]; }
}

__global__ void lilj_kernel(const float* __restrict__ x2, const float* __restrict__ v,
                            float* __restrict__ li, float* __restrict__ lj) {
    int lane = threadIdx.x & 63;
    int wv = threadIdx.x >> 6;
    int node = blockIdx.x * 4 + wv;
    float4 xa = reinterpret_cast<const float4*>(x2)[(size_t)node * 64 + lane];
    float4 va = reinterpret_cast<const float4*>(v)[lane];
    float4 vb = reinterpret_cast<const float4*>(v + HDIM)[lane];
    float a = xa.x * va.x + xa.y * va.y + xa.z * va.z + xa.w * va.w;
    float b = xa.x * vb.x + xa.y * vb.y + xa.z * vb.z + xa.w * vb.w;
#pragma unroll
    for (int off = 32; off > 0; off >>= 1) {
        a += __shfl_down(a, off);
        b += __shfl_down(b, off);
    }
    if (lane == 0) {
        li[node] = a + v[512];
        lj[node] = b + v[513];
    }
}

__global__ void edge_out(const float* __restrict__ li, const float* __restrict__ lj,
                         float* __restrict__ out) {
    int i = blockIdx.y;
    int j4 = blockIdx.x * blockDim.x + threadIdx.x;
    float a = li[i];
    float4 b = reinterpret_cast<const float4*>(lj)[j4];
    float4 r = {a + b.x, a + b.y, a + b.z, a + b.w};
    reinterpret_cast<float4*>(out)[(size_t)i * (N_NODES / 4) + j4] = r;
}

extern "C" void kernel_launch(void* const* d_in, const int* in_sizes, int n_in,
                              void* d_out, int out_size, void* d_ws, size_t ws_size,
                              hipStream_t stream) {
    const float* x      = (const float*)d_in[0];
    const int*   ei     = (const int*)d_in[1];
    const float* w0a    = (const float*)d_in[2];
    const float* b0a    = (const float*)d_in[3];
    const float* w0b    = (const float*)d_in[4];
    const float* b0b    = (const float*)d_in[5];
    const float* w1a    = (const float*)d_in[6];
    const float* b1a    = (const float*)d_in[7];
    const float* w1b    = (const float*)d_in[8];
    const float* b1b    = (const float*)d_in[9];
    const float* w_out  = (const float*)d_in[10];
    const float* b_out  = (const float*)d_in[11];
    const float* w_edge = (const float*)d_in[12];
    const float* b_edge = (const float*)d_in[13];
    const int* src = ei;
    const int* dst = ei + NEDGE;

    float* ws  = (float*)d_ws;
    float* h0  = ws;                                  // N*128
    float* t01 = h0  + (size_t)N_NODES * IN_DIM;      // N*256
    float* x12 = t01 + (size_t)N_NODES * HDIM;        // N*256
    float* h1  = x12 + (size_t)N_NODES * HDIM;        // N*256
    float* v   = h1  + (size_t)N_NODES * HDIM;        // 544
    float* li  = v + 544;                             // N
    float* lj  = li + N_NODES;                        // N
    int*   deg    = (int*)(lj + N_NODES);             // N
    int*   offs   = deg + N_NODES;                    // N+1
    int*   cursor = offs + N_NODES + 1;               // N
    int*   bucket = cursor + N_NODES;                 // E
    float* out = (float*)d_out;

    dim3 gGemm(HDIM / 64, N_NODES / 64);

    // ---- CSR build (once, shared by both layers) ----
    hipMemsetAsync(deg, 0, N_NODES * sizeof(int), stream);
    hist_kernel<<<NEDGE / 256, 256, 0, stream>>>(dst, deg);
    build_scan<<<1, 1024, 0, stream>>>(deg, offs, cursor);
    fill_kernel<<<NEDGE / 256, 256, 0, stream>>>(src, dst, cursor, bucket);

    // ---- layer 0 ----
    aggregate128<<<N_NODES / 4, 256, 0, stream>>>(x, offs, bucket, h0);
    gemm_bias_relu<IN_DIM><<<gGemm, 256, 0, stream>>>(h0, w0a, b0a, t01);
    gemm_bias_relu<HDIM><<<gGemm, 256, 0, stream>>>(t01, w0b, b0b, x12);

    // ---- layer 1 ----
    aggregate256<<<N_NODES / 4, 256, 0, stream>>>(x12, offs, bucket, h1);
    gemm_bias_relu<HDIM><<<gGemm, 256, 0, stream>>>(h1, w1a, b1a, t01);
    gemm_bias_relu<HDIM><<<gGemm, 256, 0, stream>>>(t01, w1b, b1b, x12);

    // ---- edge head ----
    prep_vec<<<1, 256, 0, stream>>>(w_out, b_out, w_edge, b_edge, v);
    lilj_kernel<<<N_NODES / 4, 256, 0, stream>>>(x12, v, li, lj);
    edge_out<<<dim3(N_NODES / 4 / 256, N_NODES), 256, 0, stream>>>(li, lj, out);
}